// Round 5
// baseline (10954.582 us; speedup 1.0000x reference)
//
#include <hip/hip_runtime.h>
#include <stdint.h>

// AutoregressiveRAM: 4095 serial steps of an 8192-neuron weightless NN.
// R5: dual-path mailbox. Base = R2-proven agent-scope tagged (data32,tag32)
// protocol (16 blocks x 512 thr). Optimistic fast path: a second mailbox
// accessed with sc0 (SE-scope) loads/stores, valid only if the team really
// shares an XCD's L2. The exact-tag protocol is SELF-CHECKING: a broken fast
// path can only TIME OUT (never deliver wrong data), so pollers fall back to
// the agent mailbox after a small fuse and permanently degrade the block via
// s_bad. Correct on every hardware behavior; fast when single-XCD L2 works.
//
// Formation: 256 blocks launched; per-XCD counters (HW_REG_XCC_ID) elect the
// first XCD to muster 16 blocks; those claim slots 0..15, rest exit.
// Pigeonhole: 256 blocks over <=16 masked ids -> some id reaches 16, CAS
// fires, >=16 claimers exist. If XCC_ID were garbage the team may span XCDs
// -> SE path times out once -> degrade to agent path (R2 perf). Output is a
// pure function of inputs either way.
//
// 2-slot overwrite safety (R2 proof): block X overwrites slot[s&1] when
// publishing state s+2, gated by X's step-(s+2) poll seeing ALL tag-(s+2)
// publishes; block Y publishes tag s+2 only after Y finished reading state
// s+1... i.e. after Y's reads of slot[s&1] completed. Holds per-path since
// publishes go to both mailboxes after reads on whichever path completed.
// Self-cleaning across replays: stale tags (prev replay, poison 0xAA) never
// equal the awaited tag; publishers overwrite lines each step.

#define BITS   8192
#define NBT    10
#define NTEAM  16
#define TPB    512
#define NPB    (BITS / NTEAM)     // 512 neurons per block (1 per thread)
#define SWORDS 256                // 8192 state bits / 32
#define WPB    (NPB / 32)         // 16 state words owned per block
#define TWORDS (NPB * 32)         // 16384 table words per block (64 KB LDS)
#define GRID   256
#define SE_FUSE   256             // ~20-40us worst once, then degrade
#define AG_FUSE   (1 << 14)
#define FORM_FUSE (1 << 20)

__global__ void pack_kernel(const float* __restrict__ tm, uint32_t* __restrict__ packed) {
    // 8192*1024 floats -> 262144 packed u32 words. One float per thread.
    int tid = blockIdx.x * blockDim.x + threadIdx.x;
    float v = tm[tid];
    unsigned long long m = __ballot(v > 0.5f);
    int lane = tid & 63;
    if ((lane & 31) == 0) {
        packed[tid >> 5] = (lane == 0) ? (uint32_t)m : (uint32_t)(m >> 32);
    }
}

// SE-scope (sc0) ops: served by the XCD-local L2 when publisher+poller share
// an XCD. If semantics differ on gfx950, polls time out -> fallback (safe).
__device__ __forceinline__ uint64_t poll_se(const uint64_t* p) {
    uint64_t v;
    asm volatile("global_load_dwordx2 %0, %1, off sc0\n\t"
                 "s_waitcnt vmcnt(0)"
                 : "=v"(v) : "v"(p) : "memory");
    return v;
}
__device__ __forceinline__ void pub_se(uint64_t* p, uint64_t v) {
    asm volatile("global_store_dwordx2 %0, %1, off sc0"
                 : : "v"(p), "v"(v) : "memory");
}

__global__ __launch_bounds__(TPB) void ram_step_kernel(
    const int* __restrict__ conn,        // [8192][10]
    const float* __restrict__ init_mem,  // [8192][16]
    const uint32_t* __restrict__ packedT,// [8192][32]
    uint64_t* __restrict__ pairs_ag,     // [2][SWORDS] agent-scope mailbox
    uint64_t* __restrict__ pairs_se,     // [2][SWORDS] SE-scope mailbox
    int* __restrict__ claim,             // [16] per-xcd, [16]=leader, [17]=slots
    float* __restrict__ out,             // [length][8192]
    int length)
{
    int xcc;
    asm volatile("s_getreg_b32 %0, hwreg(HW_REG_XCC_ID)" : "=s"(xcc));
    xcc &= 0xF;

    __shared__ int s_slot;
    __shared__ int s_bad;                // monotone 0->1: SE path broken
    const int t = threadIdx.x;
    if (t == 0) {
        s_bad = 0;
        int slot = -1;
        int mine = __hip_atomic_fetch_add(&claim[xcc], 1,
                        __ATOMIC_RELAXED, __HIP_MEMORY_SCOPE_AGENT);
        if (mine == NTEAM - 1) {          // my XCD just mustered NTEAM blocks
            int expected = 0;
            __hip_atomic_compare_exchange_strong(&claim[16], &expected,
                        xcc | 0x100, __ATOMIC_RELAXED, __ATOMIC_RELAXED,
                        __HIP_MEMORY_SCOPE_AGENT);
        }
        int lead = 0, fuse = 0;
        do {
            lead = __hip_atomic_load(&claim[16],
                        __ATOMIC_RELAXED, __HIP_MEMORY_SCOPE_AGENT);
        } while (lead == 0 && ++fuse < FORM_FUSE);
        if (lead != 0 && (lead & 0xFF) == xcc) {
            int s = __hip_atomic_fetch_add(&claim[17], 1,
                        __ATOMIC_RELAXED, __HIP_MEMORY_SCOPE_AGENT);
            if (s < NTEAM) slot = s;
        }
        s_slot = slot;
    }
    __syncthreads();
    const int b = s_slot;
    if (b < 0) return;                    // not a team member

    __shared__ uint32_t st[2][SWORDS + 1];  // double-buffered state + pos word
    __shared__ uint32_t tbl[TWORDS];        // this block's packed RAM slice

    {   // stage 64 KB lookup slice: 8 x dwordx4 per thread, coalesced
        const uint32_t* tp = packedT + (size_t)b * TWORDS;
#pragma unroll
        for (int k = 0; k < 8; ++k) {
            int w = (k * TPB + t) * 4;
            *(uint4*)&tbl[w] = *(const uint4*)(tp + w);
        }
    }

    int c[NBT];
#pragma unroll
    for (int j = 0; j < NBT; ++j) c[j] = conn[(b * NPB + t) * NBT + j];

    const int lane = t & 63;
    const int n = b * NPB + t;            // this thread's neuron
    const int gw = b * WPB + (t >> 6) * 2;// this wave's global state-word base
    bool fast = true;

    // step 0: pos bits of 0 all zero -> addr 0 -> initial_memory[:,0]
    float v0 = init_mem[n << 4];
    int bit = (v0 > 0.5f) ? 1 : 0;
    unsigned long long m = __ballot(bit);
    if (lane == 0) {
        const uint64_t tag = 1ull << 32;  // tag(state s) = s+1
        uint64_t w0 = tag | (uint32_t)m, w1 = tag | (uint32_t)(m >> 32);
        pub_se(&pairs_se[gw], w0);
        pub_se(&pairs_se[gw + 1], w1);
        __hip_atomic_store(&pairs_ag[gw], w0,
                           __ATOMIC_RELAXED, __HIP_MEMORY_SCOPE_AGENT);
        __hip_atomic_store(&pairs_ag[gw + 1], w1,
                           __ATOMIC_RELAXED, __HIP_MEMORY_SCOPE_AGENT);
        st[0][gw]     = (uint32_t)m;
        st[0][gw + 1] = (uint32_t)(m >> 32);
    }
    out[n] = v0;

    for (int i = 1; i < length; ++i) {
        uint32_t* sb = st[(i - 1) & 1];   // buffer holding state i-1
        const uint32_t want = (uint32_t)i;
        const int par = (i - 1) & 1;

        if (t == 0) {
            // pos bits of step i: x[8192+j] = (i >> (3-j)) & 1, j=0..3
            sb[SWORDS] = ((i >> 3) & 1) | (((i >> 2) & 1) << 1) |
                         (((i >> 1) & 1) << 2) | ((i & 1) << 3);
        }
        if (t < SWORDS && (t >> 4) != b) {
            uint64_t pv = 0;
            bool ok = false;
            if (fast) {                   // optimistic L2-local path
                const uint64_t* p = &pairs_se[par * SWORDS + t];
                for (int f = 0; f < SE_FUSE; ++f) {
                    pv = poll_se(p);
                    if ((uint32_t)(pv >> 32) == want) { ok = true; break; }
                }
                if (!ok) s_bad = 1;       // degrade block from next step
            }
            if (!ok) {                    // proven agent-scope path
                const uint64_t* p = &pairs_ag[par * SWORDS + t];
                int f = 0;
                do {
                    pv = __hip_atomic_load(p, __ATOMIC_RELAXED,
                                           __HIP_MEMORY_SCOPE_AGENT);
                } while ((uint32_t)(pv >> 32) != want && ++f < AG_FUSE);
            }
            sb[t] = (uint32_t)pv;
        }
        __syncthreads();                  // single barrier per step
        if (s_bad) fast = false;          // benign race: monotone flag

        // gather 10 bits -> 10-bit address (conn[0] is MSB)
        uint32_t addr = 0;
#pragma unroll
        for (int j = 0; j < NBT; ++j) {
            int cc = c[j];
            addr = (addr << 1) | ((sb[cc >> 5] >> (cc & 31)) & 1u);
        }
        uint32_t pw = tbl[(t << 5) + (addr >> 5)];   // LDS lookup
        bit = (pw >> (addr & 31)) & 1;

        // publish state i FIRST (critical path), out-store after
        m = __ballot(bit);
        if (lane == 0) {
            const uint64_t tag = ((uint64_t)(i + 1)) << 32;
            const int base = (i & 1) * SWORDS + gw;
            uint64_t w0 = tag | (uint32_t)m, w1 = tag | (uint32_t)(m >> 32);
            if (fast) {
                pub_se(&pairs_se[base], w0);
                pub_se(&pairs_se[base + 1], w1);
            }
            __hip_atomic_store(&pairs_ag[base], w0,
                               __ATOMIC_RELAXED, __HIP_MEMORY_SCOPE_AGENT);
            __hip_atomic_store(&pairs_ag[base + 1], w1,
                               __ATOMIC_RELAXED, __HIP_MEMORY_SCOPE_AGENT);
            st[i & 1][gw]     = (uint32_t)m;
            st[i & 1][gw + 1] = (uint32_t)(m >> 32);
        }
        out[(size_t)i * BITS + n] = (float)bit;
    }
}

extern "C" void kernel_launch(void* const* d_in, const int* in_sizes, int n_in,
                              void* d_out, int out_size, void* d_ws, size_t ws_size,
                              hipStream_t stream) {
    const float* tm = (const float*)d_in[0];     // transition_memory [8192][1024]
    const float* im = (const float*)d_in[1];     // initial_memory    [8192][16]
    const int*   tc = (const int*)d_in[2];       // transition_connections [8192][10]
    // d_in[3] (initial_connections) unused: pos_bits(0)==0 -> addr 0.
    const int length = out_size / BITS;

    uint32_t* packed   = (uint32_t*)d_ws;                                 // 1 MB
    uint64_t* pairs_ag = (uint64_t*)((char*)d_ws + (1 << 20));            // 4 KB
    uint64_t* pairs_se = (uint64_t*)((char*)d_ws + (1 << 20) + 4096);     // 4 KB
    int*      claim    = (int*)((char*)d_ws + (1 << 20) + 8192);          // 128 B

    // Zero agent mailbox + SE mailbox + formation counters each call/replay.
    hipMemsetAsync((char*)d_ws + (1 << 20), 0, 8192 + 128, stream);

    // Pack transition RAM to bits: 8192*1024 floats, 1 thread each.
    pack_kernel<<<dim3((BITS * 1024) / 256), dim3(256), 0, stream>>>(tm, packed);

    // 256 blocks: pigeonhole guarantees one XCD musters a full 16-block team.
    ram_step_kernel<<<dim3(GRID), dim3(TPB), 0, stream>>>(
        tc, im, packed, pairs_ag, pairs_se, claim, (float*)d_out, length);
}

// Round 6
// 6215.935 us; speedup vs baseline: 1.7623x; 1.7623x over previous
//
#include <hip/hip_runtime.h>
#include <stdint.h>

// AutoregressiveRAM: 4095 serial steps of an 8192-neuron weightless NN.
// R6 = R2-proven base (16 blocks x 512 thr, agent-scope tagged mailbox,
// plain grid, no formation/SE experiments) + three sound micros:
//   (a) double-buffered LDS state -> ONE barrier per step
//   (b) 64KB per-block LDS-staged lookup table (lookup off the L2 path)
//   (c) publish-before-out-store (tag store not queued behind output write)
//
// Mailbox protocol (exact-tag, 2 slots): state s -> slot[s&1], 8B word =
// (data32 lo, tag32=s+1 hi) so tag travels WITH data (one RTT, self-checking:
// a stale/garbage word can never match the awaited tag).
// Overwrite safety: block X overwrites slot[i&1] publishing state i only
// after X's iter-i poll saw ALL tag-i publishes; block Y publishes tag i only
// after Y's iter-(i-1) reads of slot[(i-2)&1]==slot[i&1] completed. ✓
// LDS buffer safety: iter i+1 pre-barrier writes touch st[i&1] only; iter i
// post-barrier reads touch st[(i-1)&1] only; own-words write st[i&1][gw] is
// ordered before iter-(i+1) gather reads by iter-(i+1)'s barrier. ✓
// Replay safety: mailbox memset to 0 each call; tags strictly positive.

#define BITS   8192
#define NBT    10
#define NBLK   16
#define TPB    512
#define NPB    (BITS / NBLK)   // 512 neurons per block (1 per thread)
#define SWORDS 256             // 8192 state bits / 32
#define WPB    (NPB / 32)      // 16 state words owned per block
#define TWORDS (NPB * 32)      // 16384 table words per block (64 KB LDS)
#define FUSE   (1 << 14)       // bounded spin; fuse expiry -> visible failure

__global__ void pack_kernel(const float* __restrict__ tm, uint32_t* __restrict__ packed) {
    // 8192*1024 floats -> 262144 packed u32 words. One float per thread.
    int tid = blockIdx.x * blockDim.x + threadIdx.x;
    float v = tm[tid];
    unsigned long long m = __ballot(v > 0.5f);
    int lane = tid & 63;
    if ((lane & 31) == 0) {
        packed[tid >> 5] = (lane == 0) ? (uint32_t)m : (uint32_t)(m >> 32);
    }
}

__global__ __launch_bounds__(TPB) void ram_step_kernel(
    const int* __restrict__ conn,        // [8192][10]
    const float* __restrict__ init_mem,  // [8192][16]
    const uint32_t* __restrict__ packedT,// [8192][32]
    uint64_t* __restrict__ pairs,        // [2][SWORDS] (data lo32, tag hi32)
    float* __restrict__ out,             // [length][8192]
    int length)
{
    const int b = blockIdx.x;
    const int t = threadIdx.x;
    const int lane = t & 63;
    const int n = b * NPB + t;             // this thread's neuron

    __shared__ uint32_t st[2][SWORDS + 1]; // double-buffered state + pos word
    __shared__ uint32_t tbl[TWORDS];       // this block's packed RAM slice

    {   // stage 64 KB lookup slice: 8 x dwordx4 per thread, coalesced
        const uint32_t* tp = packedT + (size_t)b * TWORDS;
#pragma unroll
        for (int k = 0; k < 8; ++k) {
            int w = (k * TPB + t) * 4;
            *(uint4*)&tbl[w] = *(const uint4*)(tp + w);
        }
    }

    // Connections are static: registers for the whole run.
    int c[NBT];
#pragma unroll
    for (int j = 0; j < NBT; ++j) c[j] = conn[n * NBT + j];

    const int gw = b * WPB + (t >> 6) * 2; // this wave's global state-word base

    // step 0: pos bits of 0 all zero -> addr 0 -> initial_memory[:,0]
    float v0 = init_mem[n << 4];
    int bit = (v0 > 0.5f) ? 1 : 0;
    unsigned long long m = __ballot(bit);
    if (lane == 0) {
        const uint64_t tag = 1ull << 32;   // tag(state s) = s+1
        __hip_atomic_store(&pairs[gw],     tag | (uint32_t)m,
                           __ATOMIC_RELAXED, __HIP_MEMORY_SCOPE_AGENT);
        __hip_atomic_store(&pairs[gw + 1], tag | (uint32_t)(m >> 32),
                           __ATOMIC_RELAXED, __HIP_MEMORY_SCOPE_AGENT);
        st[0][gw]     = (uint32_t)m;       // own slice direct to LDS buf 0
        st[0][gw + 1] = (uint32_t)(m >> 32);
    }
    out[n] = v0;

    for (int i = 1; i < length; ++i) {
        uint32_t* sb = st[(i - 1) & 1];    // buffer holding state i-1
        const uint32_t want = (uint32_t)i; // tag of state i-1

        if (t == 0) {
            // pos bits of step i: x[8192+j] = (i >> (3-j)) & 1, j=0..3
            sb[SWORDS] = ((i >> 3) & 1) | (((i >> 2) & 1) << 1) |
                         (((i >> 1) & 1) << 2) | ((i & 1) << 3);
        }
        if (t < SWORDS && (t >> 4) != b) { // poll all remote state words
            const uint64_t* p = &pairs[((i - 1) & 1) * SWORDS + t];
            uint64_t pv;
            int fuse = 0;
            do {
                pv = __hip_atomic_load(p, __ATOMIC_RELAXED,
                                       __HIP_MEMORY_SCOPE_AGENT);
            } while ((uint32_t)(pv >> 32) != want && ++fuse < FUSE);
            sb[t] = (uint32_t)pv;
        }
        __syncthreads();                   // single barrier per step

        // gather 10 bits -> 10-bit address (conn[0] is MSB)
        uint32_t addr = 0;
#pragma unroll
        for (int j = 0; j < NBT; ++j) {
            int cc = c[j];
            addr = (addr << 1) | ((sb[cc >> 5] >> (cc & 31)) & 1u);
        }
        uint32_t pw = tbl[(t << 5) + (addr >> 5)];   // LDS lookup (~120cy)
        bit = (pw >> (addr & 31)) & 1;

        // publish state i FIRST (critical path), out-store after
        m = __ballot(bit);
        if (lane == 0) {
            const uint64_t tag = ((uint64_t)(i + 1)) << 32;
            const int base = (i & 1) * SWORDS + gw;
            __hip_atomic_store(&pairs[base],     tag | (uint32_t)m,
                               __ATOMIC_RELAXED, __HIP_MEMORY_SCOPE_AGENT);
            __hip_atomic_store(&pairs[base + 1], tag | (uint32_t)(m >> 32),
                               __ATOMIC_RELAXED, __HIP_MEMORY_SCOPE_AGENT);
            st[i & 1][gw]     = (uint32_t)m;   // own slice direct to LDS
            st[i & 1][gw + 1] = (uint32_t)(m >> 32);
        }
        out[(size_t)i * BITS + n] = (float)bit;
    }
}

extern "C" void kernel_launch(void* const* d_in, const int* in_sizes, int n_in,
                              void* d_out, int out_size, void* d_ws, size_t ws_size,
                              hipStream_t stream) {
    const float* tm = (const float*)d_in[0];     // transition_memory [8192][1024]
    const float* im = (const float*)d_in[1];     // initial_memory    [8192][16]
    const int*   tc = (const int*)d_in[2];       // transition_connections [8192][10]
    // d_in[3] (initial_connections) unused: pos_bits(0)==0 -> addr 0.
    const int length = out_size / BITS;

    uint32_t* packed = (uint32_t*)d_ws;                              // 1 MB
    uint64_t* pairs  = (uint64_t*)((char*)d_ws + (1 << 20));         // 4 KB

    // Clean mailbox every call/replay (graph-capturable memset node).
    hipMemsetAsync(pairs, 0, 2 * SWORDS * sizeof(uint64_t), stream);

    // Pack transition RAM to bits: 8192*1024 floats, 1 thread each.
    pack_kernel<<<dim3((BITS * 1024) / 256), dim3(256), 0, stream>>>(tm, packed);

    // Persistent recurrence kernel: 16 blocks (always co-resident on 256 CUs).
    ram_step_kernel<<<dim3(NBLK), dim3(TPB), 0, stream>>>(
        tc, im, packed, pairs, (float*)d_out, length);
}

// Round 8
// 5632.659 us; speedup vs baseline: 1.9448x; 1.1036x over previous
//
#include <hip/hip_runtime.h>
#include <stdint.h>

// AutoregressiveRAM: 4095 serial steps of an 8192-neuron weightless NN.
// R8 = R2-EXACT skeleton (empirically best, 5.59ms: 16 blocks x 512 thr,
// two barriers, single-buffer LDS state, L2 table lookup, out-store-then-
// publish, agent-scope tagged mailbox, vmcnt(0)-blocking spin) + ONE change:
//   pollers execute s_sleep(4) (~256cy) before their FIRST poll load.
//   Rationale: (a) publish stores get an uncontested window to the L3
//   coherence point (R6 showed removing the barrier that provided this
//   window cost ~160ns/step; R5 showed poll-storm-vs-publish contention
//   catastrophically); (b) the first sample otherwise lands before publish
//   visibility (~300-500cy commit) and is guaranteed wasted; (c) aligning
//   all 240 pollers' first sample just after typical visibility collapses
//   the 240-word max-statistic (~1.5*RTT tail) toward ~1*RTT.
//
// Protocol (R2-proven, unchanged): state s -> mailbox slot[s&1], 8B word =
// (data32 lo, tag32 = s+1 hi): tag travels WITH data -> one RTT, self-
// checking (stale/garbage words never match the awaited tag; fuse expiry
// yields garbage -> visible test failure, never silent corruption).
// Overwrite safety: block X overwrites slot[i&1] publishing state i only
// after X's iter-i poll saw ALL tag-i publishes; block Y publishes tag i
// only after Y's iter-(i-1) reads of that slot completed. Replay-safe:
// mailbox memset to 0 each call; tags are strictly positive.

#define BITS   8192
#define NBT    10
#define NBLK   16
#define TPB    512
#define NPB    (BITS / NBLK)   // 512 neurons per block (1 per thread)
#define SWORDS 256             // 8192 state bits / 32
#define WPB    (NPB / 32)      // 16 state words owned per block
#define FUSE   (1 << 14)       // bounded spin; expiry -> visible failure

__global__ void pack_kernel(const float* __restrict__ tm, uint32_t* __restrict__ packed) {
    // 8192*1024 floats -> 262144 packed u32 words. One float per thread.
    int tid = blockIdx.x * blockDim.x + threadIdx.x;
    float v = tm[tid];
    unsigned long long m = __ballot(v > 0.5f);
    int lane = tid & 63;
    if ((lane & 31) == 0) {
        packed[tid >> 5] = (lane == 0) ? (uint32_t)m : (uint32_t)(m >> 32);
    }
}

__global__ __launch_bounds__(TPB) void ram_step_kernel(
    const int* __restrict__ conn,        // [8192][10]
    const float* __restrict__ init_mem,  // [8192][16]
    const uint32_t* __restrict__ packedT,// [8192][32]
    unsigned long long* __restrict__ pairs, // [2][SWORDS] (data lo32, tag hi32)
    float* __restrict__ out,             // [length][8192]
    int length)
{
    const int b = blockIdx.x;
    const int t = threadIdx.x;
    const int lane = t & 63;
    const int n = b * NPB + t;           // this thread's neuron

    __shared__ uint32_t st[SWORDS + 1];  // full state + pos-bits word

    // Connections are static: keep in registers for the whole run.
    int c[NBT];
#pragma unroll
    for (int j = 0; j < NBT; ++j) c[j] = conn[n * NBT + j];

    // ---- step 0: pos bits of 0 are all zero -> addr 0 -> initial_memory[:,0]
    float v0 = init_mem[n << 4];
    out[n] = v0;
    int bit = (v0 > 0.5f) ? 1 : 0;
    unsigned long long m = __ballot(bit);
    const int gw = b * WPB + (t >> 6) * 2;  // this wave's global state-word base
    if (lane == 0) {
        const unsigned long long tag = 1ull << 32;  // tag(step s) = s+1
        __hip_atomic_store(&pairs[gw],     tag | (uint32_t)m,
                           __ATOMIC_RELAXED, __HIP_MEMORY_SCOPE_AGENT);
        __hip_atomic_store(&pairs[gw + 1], tag | (uint32_t)(m >> 32),
                           __ATOMIC_RELAXED, __HIP_MEMORY_SCOPE_AGENT);
        st[gw]     = (uint32_t)m;        // own slice goes straight to LDS
        st[gw + 1] = (uint32_t)(m >> 32);
    }

    for (int i = 1; i < length; ++i) {
        const int parity = (i - 1) & 1;
        const uint32_t want = (uint32_t)i;          // waiting for tag of step i-1

        if (t == 0) {
            // pos bits of step i: x[8192+j] = (i >> (3-j)) & 1
            st[SWORDS] = ((i >> 3) & 1) | (((i >> 2) & 1) << 1) |
                         (((i >> 1) & 1) << 2) | ((i & 1) << 3);
        }
        if (t < SWORDS && (t >> 4) != b) {          // poll everyone else's words
            // Give remote publishes an uncontested commit window, and align
            // the first sample to land just after typical visibility.
            __builtin_amdgcn_s_sleep(4);            // ~256 cycles
            unsigned long long* p = &pairs[parity * SWORDS + t];
            unsigned long long pv;
            int fuse = 0;
            do {
                pv = __hip_atomic_load(p, __ATOMIC_RELAXED, __HIP_MEMORY_SCOPE_AGENT);
            } while ((uint32_t)(pv >> 32) != want && ++fuse < FUSE);
            st[t] = (uint32_t)pv;
        }
        __syncthreads();

        // gather 10 bits -> 10-bit address (conn[0] is MSB)
        uint32_t addr = 0;
#pragma unroll
        for (int j = 0; j < NBT; ++j) {
            int cc = c[j];
            uint32_t w = st[cc >> 5];
            addr = (addr << 1) | ((w >> (cc & 31)) & 1u);
        }
        uint32_t pw = packedT[(n << 5) + (addr >> 5)];
        bit = (pw >> (addr & 31)) & 1;
        out[(size_t)i * BITS + n] = (float)bit;

        // publish own slice for step i (R2 order: after the out-store)
        m = __ballot(bit);
        if (lane == 0) {
            const unsigned long long tag = ((unsigned long long)(i + 1)) << 32;
            const int base = (i & 1) * SWORDS + gw;
            __hip_atomic_store(&pairs[base],     tag | (uint32_t)m,
                               __ATOMIC_RELAXED, __HIP_MEMORY_SCOPE_AGENT);
            __hip_atomic_store(&pairs[base + 1], tag | (uint32_t)(m >> 32),
                               __ATOMIC_RELAXED, __HIP_MEMORY_SCOPE_AGENT);
        }
        __syncthreads();                 // everyone done reading step i-1 state
        if (lane == 0) {                 // now safe to refresh own LDS words
            st[gw]     = (uint32_t)m;
            st[gw + 1] = (uint32_t)(m >> 32);
        }
    }
}

extern "C" void kernel_launch(void* const* d_in, const int* in_sizes, int n_in,
                              void* d_out, int out_size, void* d_ws, size_t ws_size,
                              hipStream_t stream) {
    const float* tm = (const float*)d_in[0];     // transition_memory [8192][1024]
    const float* im = (const float*)d_in[1];     // initial_memory    [8192][16]
    const int*   tc = (const int*)d_in[2];       // transition_connections [8192][10]
    // d_in[3] (initial_connections) is provably unused: pos_bits(0)==0 -> addr 0.
    const int length = out_size / BITS;

    uint32_t* packed = (uint32_t*)d_ws;                                   // 1 MB
    unsigned long long* pairs =
        (unsigned long long*)((char*)d_ws + (1 << 20));                   // 4 KB

    // Clean mailbox every call/replay (graph-capturable memset node).
    hipMemsetAsync(pairs, 0, 2 * SWORDS * sizeof(unsigned long long), stream);

    // Pack transition RAM to bits: 8192*1024 floats, 1 thread each.
    pack_kernel<<<dim3((BITS * 1024) / 256), dim3(256), 0, stream>>>(tm, packed);

    // Persistent recurrence kernel: 16 blocks (always co-resident on 256 CUs).
    ram_step_kernel<<<dim3(NBLK), dim3(TPB), 0, stream>>>(
        tc, im, packed, pairs, (float*)d_out, length);
}